// Round 4
// baseline (232.085 us; speedup 1.0000x reference)
//
#include <hip/hip_runtime.h>
#include <math.h>

#define EPSF 1e-9f
#define KK 128
#define MTOP 10   // m

// R11 = R7/R10 structure + LDS-staged P via async global_load_lds DMA.
//
// R10 post-mortem: VGPR came back 36 (<52 falsification bound) -> hipcc
// DE-PIPELINED the register prefetch again (R9: same). Durable lesson:
// source-level register prefetch of global loads is un-enforceable with
// hipcc; the only prefetch it cannot sink is global_load_lds DMA (drained
// at the barrier, not at a register use).
//
// This version:
//  * P staged ONCE per block into LDS (was: each of 4 waves streamed the
//    full 64KB P from global = 4x re-read, latency exposed per 4-row group).
//  * Double-buffered 16-row chunks (8KB x2). Chunk = 8 rows of k-half 0 +
//    8 rows of k-half 1, so both half-waves compute every chunk.
//  * 2-phase schedule per chunk: issue-DMA(next) -> compute(cur) ->
//    __syncthreads (auto vmcnt(0) drain) -> swap. Loads fly under FMAs.
//  * Wave w stages local rows 4w..4w+3 via 2 DMA issues (LDS dest is
//    wave-uniform base + lane*16 -> rows must be LDS-linear; they are).
//  * GEMM inner loop now reads p from LDS (b128), zero p-address VALU.
//  * LDS 26.6KB/block -> 6 blocks/CU; launch_bounds(256,6) caps VGPR ~84.
// Everything after the GEMM is verified-identical (R7): shfl k-half
// combine + identity trick, butterfly m1, lockstep ballot bisection
// (exact 11th largest), per-block partials, 2*B-float workspace.
//
// LESSONS (R1-R10): compile-time-constant register-array indices; no
// helper-by-reference; small loop bodies (no full GEMM unroll: I$);
// launch_bounds 2nd arg caps VGPR - don't starve; workspace stays 2*B.

#define GLDS16(G, L) __builtin_amdgcn_global_load_lds(                    \
    (const __attribute__((address_space(1))) void*)(G),                   \
    (__attribute__((address_space(3))) void*)(L), 16, 0, 0)

// Wave w stages local rows 4w+2I, 4w+2I+1 of chunk T into sP[BUF].
// Global row = 8T + rowoff + local_row (rowoff folds the hi-half offset).
// Per-lane global addr; WAVE-UNIFORM LDS base (HW adds lane*16).
#define STAGE_ISSUE(T, BUF, I)                                            \
    GLDS16(Pb + (size_t)(((T) << 3) + rowoff + (wave << 2) + ((I) << 1)   \
                         + l5) * KK + (lx << 2),                          \
           &sP[BUF][((wave << 2) + ((I) << 1)) * KK])
#define STAGE_CHUNK(T, BUF) { STAGE_ISSUE(T, BUF, 0); STAGE_ISSUE(T, BUF, 1); }

// One 4-k FMA group of chunk T, group G (0/1), p from LDS buffer BUF.
#define FMA5G(T, BUF, G)                                                  \
    {                                                                     \
        const float* pbse = &sP[BUF][((sg << 3) + ((G) << 2)) * KK + j4]; \
        float4 p0 = *(const float4*)(pbse + 0 * KK);                      \
        float4 p1 = *(const float4*)(pbse + 1 * KK);                      \
        float4 p2 = *(const float4*)(pbse + 2 * KK);                      \
        float4 p3 = *(const float4*)(pbse + 3 * KK);                      \
        const int soff = kbase + ((T) << 3) + ((G) << 2);                 \
        _Pragma("unroll")                                                 \
        for (int r = 0; r < 5; ++r) {                                     \
            float4 s = *(const float4*)&sS[(r0 + r) * KK + soff];         \
            acc[r].x = fmaf(s.x, p0.x, acc[r].x);                         \
            acc[r].y = fmaf(s.x, p0.y, acc[r].y);                         \
            acc[r].z = fmaf(s.x, p0.z, acc[r].z);                         \
            acc[r].w = fmaf(s.x, p0.w, acc[r].w);                         \
            acc[r].x = fmaf(s.y, p1.x, acc[r].x);                         \
            acc[r].y = fmaf(s.y, p1.y, acc[r].y);                         \
            acc[r].z = fmaf(s.y, p1.z, acc[r].z);                         \
            acc[r].w = fmaf(s.y, p1.w, acc[r].w);                         \
            acc[r].x = fmaf(s.z, p2.x, acc[r].x);                         \
            acc[r].y = fmaf(s.z, p2.y, acc[r].y);                         \
            acc[r].z = fmaf(s.z, p2.z, acc[r].z);                         \
            acc[r].w = fmaf(s.z, p2.w, acc[r].w);                         \
            acc[r].x = fmaf(s.w, p3.x, acc[r].x);                         \
            acc[r].y = fmaf(s.w, p3.y, acc[r].y);                         \
            acc[r].z = fmaf(s.w, p3.z, acc[r].z);                         \
            acc[r].w = fmaf(s.w, p3.w, acc[r].w);                         \
        }                                                                 \
    }

__global__ __launch_bounds__(256, 6) void fused_kernel(
    const float* __restrict__ y_pred, const float* __restrict__ y_true,
    const float* __restrict__ P, const float* __restrict__ samples,
    float* __restrict__ partial /* [2*B]: per-block {logmse_i, penalty_i} */)
{
    const int tid   = threadIdx.x;
    const int wave  = tid >> 6;
    const int lane  = tid & 63;
    const int b     = blockIdx.x;
    const int r0    = wave * 5;
    const int sg    = lane >> 5;     // k-segment of the half-wave
    const int c     = lane & 31;     // column group
    const int j4    = c << 2;
    const int kbase = sg << 6;       // 0 or 64
    const int l5    = lane >> 5;     // staging: row-within-issue
    const int lx    = lane & 31;     // staging: 16B slot within row
    const int rowoff = (wave >= 2) ? 56 : 0;  // hi-half rows: 64+(il-8)=56+il

    const float* __restrict__ Pb = P + ((size_t)b << 14);            // b*128*128
    const float* __restrict__ Sb = samples + (size_t)b * (20 * KK);  // b*20*128

    __shared__ float sS[20 * KK];    // S rows: broadcast + identity values
    __shared__ float sP[2][16 * KK]; // double-buffered P chunk (16 rows)
    __shared__ float red[4];

    // ---- stage S into LDS, block-cooperative, coalesced float2 ----
#pragma unroll
    for (int i = 0; i < 5; ++i) {
        const int idx = (i * 256 + tid) * 2;
        *(float2*)&sS[idx] = *(const float2*)(Sb + idx);
    }

    float4 acc[5];
#pragma unroll
    for (int r = 0; r < 5; ++r) acc[r] = make_float4(0.f, 0.f, 0.f, 0.f);

    // ---- prologue: DMA chunk 0; barrier drains DMA + sS writes ----
    STAGE_CHUNK(0, 0);
    __syncthreads();

    // ---- 2-phase pipelined GEMM: issue(t+1) || compute(t) ----
    int cur = 0;
#pragma unroll 1
    for (int t = 0; t < 7; ++t) {
        STAGE_CHUNK(t + 1, cur ^ 1);   // DMA in flight under the FMAs
        FMA5G(t, cur, 0)
        FMA5G(t, cur, 1)
        __syncthreads();               // vmcnt(0)+barrier: chunk t+1 ready
        cur ^= 1;
    }
    FMA5G(7, cur, 0)                   // epilogue chunk, no prefetch
    FMA5G(7, cur, 1)

    // ---- combine k-halves; upper half-wave switches to identity values ----
    float w0[5], w1[5], w2[5], w3[5];
#pragma unroll
    for (int r = 0; r < 5; ++r) {
        float ax = acc[r].x + __shfl_xor(acc[r].x, 32, 64);
        float ay = acc[r].y + __shfl_xor(acc[r].y, 32, 64);
        float az = acc[r].z + __shfl_xor(acc[r].z, 32, 64);
        float aw = acc[r].w + __shfl_xor(acc[r].w, 32, 64);
        float4 idv = *(const float4*)&sS[(r0 + r) * KK + j4];
        w0[r] = fabsf(sg ? idv.x : ax);
        w1[r] = fabsf(sg ? idv.y : ay);
        w2[r] = fabsf(sg ? idv.z : az);
        w3[r] = fabsf(sg ? idv.w : aw);
    }

    // ---- m1 per row: lane max + 6-shfl butterfly (5 chains interleave) ----
    float mx[5];
#pragma unroll
    for (int r = 0; r < 5; ++r) {
        float lm = fmaxf(fmaxf(w0[r], w1[r]), fmaxf(w2[r], w3[r]));
#pragma unroll
        for (int d = 32; d >= 1; d >>= 1)
            lm = fmaxf(lm, __shfl_xor(lm, d, 64));
        mx[r] = lm;
    }

    // ---- m11 per row: LOCKSTEP ballot bisection on float bit patterns ----
    unsigned lo[5], hi[5];
#pragma unroll
    for (int r = 0; r < 5; ++r) { lo[r] = 0u; hi[r] = __float_as_uint(mx[r]); }

    while (lo[0] < hi[0] || lo[1] < hi[1] || lo[2] < hi[2] ||
           lo[3] < hi[3] || lo[4] < hi[4]) {
#pragma unroll
        for (int r = 0; r < 5; ++r) {
            unsigned mid = lo[r] + ((hi[r] - lo[r] + 1u) >> 1);
            float mf = __uint_as_float(mid);
            int cnt = __popcll(__ballot(w0[r] > mf)) + __popcll(__ballot(w1[r] > mf))
                    + __popcll(__ballot(w2[r] > mf)) + __popcll(__ballot(w3[r] > mf));
            bool g = cnt >= (MTOP + 1);
            lo[r] = g ? mid : lo[r];
            hi[r] = g ? hi[r] : mid - 1u;
        }
    }

    float hmax = 0.f;
#pragma unroll
    for (int r = 0; r < 5; ++r) {
        float m11 = __uint_as_float(lo[r] + 1u);   // exact 11th-largest
        hmax = fmaxf(hmax, mx[r] / (m11 + EPSF));  // wave-uniform
    }

    // ---- combine 4 waves; per-block partials (no atomics) ----
    if (lane == 0) red[wave] = hmax;
    __syncthreads();
    if (tid == 0) {
        float hb  = fmaxf(fmaxf(red[0], red[1]), fmaxf(red[2], red[3]));
        float ypv = y_pred[b];
        float yp  = fmaxf(ypv, EPSF);
        float yt  = fmaxf(y_true[b], EPSF);
        float d   = log2f(yt) - log2f(yp);
        partial[2 * b]     = d * d;
        partial[2 * b + 1] = fmaxf(hb - ypv, 0.f);
    }
}

__global__ __launch_bounds__(256) void finalize_kernel(
    const float* __restrict__ partial, float* __restrict__ out, float invB)
{
    const int t = threadIdx.x;
    float sl = 0.f, sp = 0.f;
#pragma unroll
    for (int i = 0; i < 8; ++i) {
        float2 v = *(const float2*)(partial + 2 * (t + i * 256));
        sl += v.x; sp += v.y;
    }
#pragma unroll
    for (int d = 32; d >= 1; d >>= 1) {
        sl += __shfl_xor(sl, d, 64);
        sp += __shfl_xor(sp, d, 64);
    }
    __shared__ float rl[4], rp[4];
    const int w = t >> 6;
    if ((t & 63) == 0) { rl[w] = sl; rp[w] = sp; }
    __syncthreads();
    if (t == 0) {
        float L = (rl[0] + rl[1] + rl[2] + rl[3]) * invB;
        float V = (rp[0] + rp[1] + rp[2] + rp[3]) * invB;
        out[0] = L + 0.5f * V;
        out[1] = L;
        out[2] = V;
    }
}

extern "C" void kernel_launch(void* const* d_in, const int* in_sizes, int n_in,
                              void* d_out, int out_size, void* d_ws, size_t ws_size,
                              hipStream_t stream) {
    const float* y_pred  = (const float*)d_in[0];
    const float* y_true  = (const float*)d_in[1];
    const float* P       = (const float*)d_in[2];
    const float* samples = (const float*)d_in[3];
    const int B = in_sizes[0];           // y_pred has B elements

    float* partial = (float*)d_ws;       // 2*B floats, fully overwritten

    fused_kernel<<<B, 256, 0, stream>>>(y_pred, y_true, P, samples, partial);
    finalize_kernel<<<1, 256, 0, stream>>>(partial, (float*)d_out, 1.0f / (float)B);
}